// Round 10
// baseline (592.784 us; speedup 1.0000x reference)
//
#include <hip/hip_runtime.h>

// ---------- problem constants ----------
#define CDIM   768
#define NSEQ   196
#define NVIEW  5
#define BN_TOT 6272       // B*N
#define SLAB   4816896    // BN_TOT*CDIM
#define WSLAB  589824     // CDIM*CDIM

typedef __attribute__((ext_vector_type(8))) short short8;  // 8 bf16 (4 VGPRs)
typedef __attribute__((ext_vector_type(4))) float f32x4;

// ---------- helpers ----------
__device__ __forceinline__ float bf_lo(unsigned u) { return __uint_as_float(u << 16); }
__device__ __forceinline__ float bf_hi(unsigned u) { return __uint_as_float(u & 0xffff0000u); }
__device__ __forceinline__ unsigned short f2bf(float f) {
  unsigned u = __float_as_uint(f);
  return (unsigned short)((u + 0x7fffu + ((u >> 16) & 1u)) >> 16);  // RNE
}
__device__ __forceinline__ unsigned pack2(float f0, float f1) {
  return (unsigned)f2bf(f0) | ((unsigned)f2bf(f1) << 16);
}
__device__ __forceinline__ float ftanh(float x) {
  x = fminf(fmaxf(x, -10.f), 10.f);
  float e = __expf(2.f * x);
  return (e - 1.f) / (e + 1.f);
}
__device__ __forceinline__ void async_cp16(const void* g, void* l) {
  __builtin_amdgcn_global_load_lds((const __attribute__((address_space(1))) unsigned*)g,
                                   (__attribute__((address_space(3))) unsigned*)l, 16, 0, 0);
}

// ---------- weight transpose fp32 -> bf16: 7 matrices of 768x768 (R0 exact) ----------
__global__ __launch_bounds__(256) void k_tr(const float* __restrict__ wv,
                                            const float* __restrict__ w1,
                                            unsigned short* __restrict__ wvT,
                                            unsigned short* __restrict__ w1aT,
                                            unsigned short* __restrict__ w1bT) {
  __shared__ float tile[32][33];
  const int m = blockIdx.z;
  const float* src;
  unsigned short* dst;
  if (m < NVIEW)      { src = wv + (size_t)m * WSLAB; dst = wvT + (size_t)m * WSLAB; }
  else if (m == NVIEW){ src = w1;                     dst = w1aT; }
  else                { src = w1 + WSLAB;             dst = w1bT; }
  const int tx = threadIdx.x, ty = threadIdx.y;
  const int x0 = blockIdx.x * 32, y0 = blockIdx.y * 32;
#pragma unroll
  for (int i = 0; i < 4; ++i)
    tile[ty + i * 8][tx] = src[(size_t)(y0 + ty + i * 8) * CDIM + x0 + tx];
  __syncthreads();
#pragma unroll
  for (int i = 0; i < 4; ++i)
    dst[(size_t)(x0 + ty + i * 8) * CDIM + y0 + tx] = f2bf(tile[tx][ty + i * 8]);
}

// ---------- single pass over x: xb[v][bn][c] = bf16(x), cb = mean over v (R0 exact) ----------
__global__ __launch_bounds__(192) void k_cvt_mean(const float* __restrict__ x,
                                                  unsigned short* __restrict__ xb,
                                                  unsigned short* __restrict__ cb) {
  const int bn = blockIdx.x;
  const int b = bn / NSEQ, n = bn % NSEQ;
  const int h = threadIdx.x * 4;
  const float* xp = x + ((size_t)(b * NVIEW) * NSEQ + n) * CDIM + h;
  float s0 = 0, s1 = 0, s2 = 0, s3 = 0;
#pragma unroll
  for (int v = 0; v < NVIEW; ++v) {
    float4 p = *(const float4*)(xp + (size_t)v * (NSEQ * CDIM));
    s0 += p.x; s1 += p.y; s2 += p.z; s3 += p.w;
    uint2 q; q.x = pack2(p.x, p.y); q.y = pack2(p.z, p.w);
    *(uint2*)(xb + ((size_t)v * BN_TOT + bn) * CDIM + h) = q;
  }
  uint2 o;
  o.x = pack2(s0 * 0.2f, s1 * 0.2f);
  o.y = pack2(s2 * 0.2f, s3 * 0.2f);
  *(uint2*)(cb + (size_t)bn * CDIM + h) = o;
}

// ---------- fragment helpers (register double-buffer) ----------
__device__ __forceinline__ void ldfrag(const unsigned short* bp, int wm, int wn,
                                       int lr, int kch, short8* af, short8* bf) {
#pragma unroll
  for (int i = 0; i < 4; ++i) af[i] = *(const short8*)(bp + (wm + i * 16 + lr) * 32 + kch);
#pragma unroll
  for (int j = 0; j < 4; ++j) bf[j] = *(const short8*)(bp + 4096 + (wn + j * 16 + lr) * 32 + kch);
}
__device__ __forceinline__ void domfma(const short8* af, const short8* bf, f32x4 acc[4][4]) {
  __builtin_amdgcn_s_setprio(1);
#pragma unroll
  for (int i = 0; i < 4; ++i)
#pragma unroll
    for (int j = 0; j < 4; ++j)
      acc[i][j] = __builtin_amdgcn_mfma_f32_16x16x32_bf16(af[i], bf[j], acc[i][j], 0, 0, 0);
  __builtin_amdgcn_s_setprio(0);
}

// ---------- 128x256-tile GEMM, 3-ring, counted vmcnt, REGISTER frag dbuf ----------
// (identical resubmission of R9 source: container-level infra failure, 3rd
//  occurrence of a signature that twice reran clean with identical source
//  (R2->R3, R6->R7); ledger re-audit in journal found no fault/hang path.)
// Delta vs R7 champion (808 TF): break the per-tile ds_read->MFMA serial
// chain. R8 falsified LDS-BW (25% less traffic, same time); per tile-pair
// wall ~3166cy vs MFMA 1242 + LDS ~1400 -> both pipes half-idle -> latency
// bound. Fix: while MFMA-ing tile kt from reg set R, ds_read tile kt+1 into
// reg set W (its DMA landed: end-of-(kt-1) vmcnt(3) proved it). Reads hide
// under the 16-MFMA window; sched_barrier(0) pins them before the cluster.
// Ledger per PHASE(kt): ldfrag(kt+1)->W ; STAGE(kt+3)->slot kt%3 (held tile
// kt, whose frags were read at kt-1 and lgkm-drained before the kt-1 end
// barrier) ; MFMA(kt)<-R ; vmcnt(3) [kt+2 landed, kt+3 in flight; kt==21:
// vmcnt(0)] ; lgkmcnt(0) [my W-reads sampled before anyone DMAs that slot] ;
// barrier. Prologue stages 0,1,2; vmcnt(3) lands 0,1; extra lgkm+barrier
// after the tile-0 ldfrag prevents the slot-0 overwrite race at kt=0.
// Loop unrolled x2 with named A/B reg sets (rule 20: static indexing).
// MODE 0 (1617 works): z<5 proj=xb_v@wvT_v ; z in[5,10) xw1=xb_v@w1aT ;
// z==10 cw1=cb@w1bT.  MODE 1 (735): pw1b_v = projb_v @ w1bT.
template <int MODE>
__global__ __launch_bounds__(512, 4) void gemm_r(const unsigned short* __restrict__ P0,
                                                 const unsigned short* __restrict__ cbp,
                                                 const unsigned short* __restrict__ wvT,
                                                 const unsigned short* __restrict__ w1aT,
                                                 const unsigned short* __restrict__ w1bT,
                                                 unsigned short* __restrict__ Q0,
                                                 unsigned short* __restrict__ Q1,
                                                 unsigned short* __restrict__ Q2) {
  extern __shared__ unsigned short ldsb[];   // 3 slots x (A 4096 + B 8192) shorts = 72 KB
  constexpr int NWG = (MODE == 0) ? 1617 : 735;
  // bijective XCD swizzle (m204)
  const int orig = blockIdx.x;
  const int qq = NWG >> 3, rr = NWG & 7, xcd = orig & 7, slot0 = orig >> 3;
  const int wk = (xcd < rr ? xcd * (qq + 1) : rr * (qq + 1) + (xcd - rr) * qq) + slot0;
  const int nt = wk % 3, mt = (wk / 3) % 49, z = wk / 147;

  const int t = threadIdx.x, w = t >> 6, lane = t & 63, lr = lane & 15, lq = lane >> 4;
  const int wm = ((w >> 2) & 1) * 64;   // 0 / 64
  const int wn = (w & 3) * 64;          // 0 / 64 / 128 / 192
  const int colBase = nt * 256, mrow0 = mt * 128;

  const unsigned short *A, *Bt;
  unsigned short* C;
  if (MODE == 0) {
    if (z == 10)    { A = cbp; Bt = w1bT; C = Q2; }
    else if (z < 5) { A = P0 + (size_t)z * SLAB;       Bt = wvT + (size_t)z * WSLAB; C = Q0 + (size_t)z * SLAB; }
    else            { A = P0 + (size_t)(z - 5) * SLAB; Bt = w1aT;                    C = Q1 + (size_t)(z - 5) * SLAB; }
  } else {
    A = P0 + (size_t)z * SLAB; Bt = w1bT; C = Q0 + (size_t)z * SLAB;
  }

  // staging sources (pre-swizzled k-chunk; DMA dest is linear: rule-21 pair)
  const int swz = ((t & 3) ^ ((t >> 3) & 3)) << 3;
  const unsigned short* gA = A  + (size_t)(mrow0 + (t >> 2)) * CDIM + swz;
  const unsigned short* gB = Bt + (size_t)(colBase + (t >> 2)) * CDIM + swz;
  // ds_read address (same involution: chunk = lq ^ ((lr>>1)&3))
  const int kch = ((lq ^ ((lr >> 1) & 3)) << 3);

  // 3 vmcnt-ops per tile: A(1) + B(2). Wave w's DMA dest = uniform base + lane*16B.
#define STAGE(kt, s) {                                                            \
    unsigned short* d_ = ldsb + (s) * 12288 + (w << 9);                           \
    async_cp16(gA + (kt) * 32, d_);                                               \
    async_cp16(gB + (kt) * 32, d_ + 4096);                                        \
    async_cp16(gB + (kt) * 32 + (size_t)128 * CDIM, d_ + 8192); }

  f32x4 acc[4][4] = {};
  short8 afA[4], bfA[4], afB[4], bfB[4];

  // prologue: stage 0,1,2 ; tiles 0,1 landed (tile 2's 3 in flight) ; read tile 0
  STAGE(0, 0); STAGE(1, 1); STAGE(2, 2);
  asm volatile("s_waitcnt vmcnt(3)" ::: "memory");
  __builtin_amdgcn_s_barrier();
  ldfrag(ldsb, wm, wn, lr, kch, afA, bfA);
  asm volatile("s_waitcnt lgkmcnt(0)" ::: "memory");   // tile-0 reads sampled...
  __builtin_amdgcn_s_barrier();                        // ...before anyone DMAs slot 0

#define PHASE(kt, afR, bfR, afW, bfW) {                                          \
    if ((kt) < 23) ldfrag(ldsb + (((kt) + 1) % 3) * 12288, wm, wn, lr, kch,      \
                          afW, bfW);                                             \
    if ((kt) <= 20) STAGE((kt) + 3, (kt) % 3);                                   \
    __builtin_amdgcn_sched_barrier(0);     /* pin reads before MFMA cluster */   \
    domfma(afR, bfR, acc);                 /* reads in flight under MFMA */      \
    if ((kt) <= 20)      { asm volatile("s_waitcnt vmcnt(3)" ::: "memory"); }    \
    else if ((kt) == 21) { asm volatile("s_waitcnt vmcnt(0)" ::: "memory"); }    \
    asm volatile("s_waitcnt lgkmcnt(0)" ::: "memory");                           \
    __builtin_amdgcn_s_barrier();                                                \
  }

  for (int kt = 0; kt < 24; kt += 2) {
    PHASE(kt,     afA, bfA, afB, bfB);
    PHASE(kt + 1, afB, bfB, afA, bfA);
  }
#undef PHASE
#undef STAGE

  // epilogue (M % 128 == 0 everywhere)
#pragma unroll
  for (int i = 0; i < 4; ++i)
#pragma unroll
    for (int j = 0; j < 4; ++j) {
      const int gr = mrow0 + wm + i * 16 + lq * 4;   // C/D: row=(lane>>4)*4+reg, col=lane&15
      const int gc = colBase + wn + j * 16 + lr;
      unsigned short* cp = C + (size_t)gr * CDIM + gc;
#pragma unroll
      for (int r = 0; r < 4; ++r)
        cp[(size_t)r * CDIM] = f2bf(acc[i][j][r]);
    }
}

// ---------- fully fused routing loop (R0 exact) ----------
__global__ __launch_bounds__(192) void k_iter3(const unsigned short* __restrict__ xw1b,
                                               const unsigned short* __restrict__ cw1,
                                               const unsigned short* __restrict__ pw1b,
                                               const unsigned short* __restrict__ projb,
                                               const float* __restrict__ b1,
                                               const float* __restrict__ w2,
                                               float* __restrict__ outc,
                                               float* __restrict__ outr) {
  __shared__ float red[3][NVIEW];
  __shared__ float aa[NVIEW];
  const int bn = blockIdx.x, t = threadIdx.x, wid = t >> 6, lane = t & 63;
  const int h = t * 4;
  const float4 bv = *(const float4*)(b1 + h);
  const float4 wv = *(const float4*)(w2 + h);
  float cw[4];
  { uint2 c = *(const uint2*)(cw1 + (size_t)bn * CDIM + h);
    cw[0] = bf_lo(c.x); cw[1] = bf_hi(c.x); cw[2] = bf_lo(c.y); cw[3] = bf_hi(c.y); }
  float xw[NVIEW][4], pf[NVIEW][4];
#pragma unroll
  for (int v = 0; v < NVIEW; ++v) {
    uint2 q = *(const uint2*)(xw1b + ((size_t)v * BN_TOT + bn) * CDIM + h);
    xw[v][0] = bf_lo(q.x) + bv.x; xw[v][1] = bf_hi(q.x) + bv.y;
    xw[v][2] = bf_lo(q.y) + bv.z; xw[v][3] = bf_hi(q.y) + bv.w;
    uint2 p = *(const uint2*)(pw1b + ((size_t)v * BN_TOT + bn) * CDIM + h);
    pf[v][0] = bf_lo(p.x); pf[v][1] = bf_hi(p.x);
    pf[v][2] = bf_lo(p.y); pf[v][3] = bf_hi(p.y);
  }
  for (int it = 0; it < 3; ++it) {
    float part[NVIEW];
#pragma unroll
    for (int v = 0; v < NVIEW; ++v) {
      float p;
      p = wv.x * ftanh(xw[v][0] + cw[0]);
      p = fmaf(wv.y, ftanh(xw[v][1] + cw[1]), p);
      p = fmaf(wv.z, ftanh(xw[v][2] + cw[2]), p);
      p = fmaf(wv.w, ftanh(xw[v][3] + cw[3]), p);
      part[v] = p;
    }
#pragma unroll
    for (int off = 32; off > 0; off >>= 1)
#pragma unroll
      for (int v = 0; v < NVIEW; ++v) part[v] += __shfl_down(part[v], off);
    if (lane == 0)
#pragma unroll
      for (int v = 0; v < NVIEW; ++v) red[wid][v] = part[v];
    __syncthreads();
    if (t == 0) {
      float s[NVIEW];
#pragma unroll
      for (int v = 0; v < NVIEW; ++v) s[v] = red[0][v] + red[1][v] + red[2][v];
      float m = s[0];
#pragma unroll
      for (int v = 1; v < NVIEW; ++v) m = fmaxf(m, s[v]);
      float a[NVIEW], sum = 0.f;
#pragma unroll
      for (int v = 0; v < NVIEW; ++v) { a[v] = __expf(s[v] - m); sum += a[v]; }
      const float inv = 1.f / sum;
#pragma unroll
      for (int v = 0; v < NVIEW; ++v) { a[v] *= inv; aa[v] = a[v]; }
      if (it == 2) {
        float ent = 0.f;
#pragma unroll
        for (int v = 0; v < NVIEW; ++v) ent -= a[v] * logf(a[v] + 1e-8f);
        outr[bn] = 1.f - ent * 0.6213349345596119f;  // 1/ln(5)
      }
    }
    __syncthreads();
    if (it < 2) {
      float n0 = 0, n1 = 0, n2 = 0, n3 = 0;
#pragma unroll
      for (int v = 0; v < NVIEW; ++v) {
        const float av = aa[v];
        n0 = fmaf(av, pf[v][0], n0); n1 = fmaf(av, pf[v][1], n1);
        n2 = fmaf(av, pf[v][2], n2); n3 = fmaf(av, pf[v][3], n3);
      }
      cw[0] = n0; cw[1] = n1; cw[2] = n2; cw[3] = n3;
    } else {
      float r0 = 0, r1 = 0, r2 = 0, r3 = 0;
#pragma unroll
      for (int v = 0; v < NVIEW; ++v) {
        const float av = aa[v];
        uint2 p = *(const uint2*)(projb + ((size_t)v * BN_TOT + bn) * CDIM + h);
        r0 = fmaf(av, bf_lo(p.x), r0); r1 = fmaf(av, bf_hi(p.x), r1);
        r2 = fmaf(av, bf_lo(p.y), r2); r3 = fmaf(av, bf_hi(p.y), r3);
      }
      float4 of; of.x = r0; of.y = r1; of.z = r2; of.w = r3;
      *(float4*)(outc + (size_t)bn * CDIM + h) = of;
    }
  }
}

extern "C" void kernel_launch(void* const* d_in, const int* in_sizes, int n_in,
                              void* d_out, int out_size, void* d_ws, size_t ws_size,
                              hipStream_t stream) {
  (void)in_sizes; (void)n_in; (void)out_size; (void)ws_size;
  const float* x  = (const float*)d_in[0];   // [B,V,N,C] fp32
  const float* wv = (const float*)d_in[1];   // [V,C,C]
  const float* w1 = (const float*)d_in[2];   // [2C,H]
  const float* b1 = (const float*)d_in[3];   // [H]
  const float* w2 = (const float*)d_in[4];   // [H,1]
  // d_in[5] = b2: uniform shift over views -> softmax-invariant, unused.

  // workspace: 86,016,000 ushorts = 172 MB (R0's exact known-safe layout)
  unsigned short* ws   = (unsigned short*)d_ws;
  unsigned short* wvT  = ws;                             //  2,949,120  [V][d][c]
  unsigned short* w1aT = ws + 2949120;                   //    589,824
  unsigned short* w1bT = ws + 3538944;                   //    589,824
  unsigned short* xb   = ws + 4128768;                   // 24,084,480  [V,BN,C]; dead after GEMM A
  unsigned short* pw1b = ws + 4128768;                   //   (aliased onto xb)
  unsigned short* projb= ws + 28213248;                  // 24,084,480
  unsigned short* xw1b = ws + 52297728;                  // 24,084,480
  unsigned short* cb   = ws + 76382208;                  //  4,816,896
  unsigned short* cw1  = ws + 81199104;                  //  4,816,896  (end: 86,016,000)

  float* outc = (float*)d_out;                           // c [B,N,C] fp32
  float* outr = outc + SLAB;                             // r [B,N]   fp32

  k_tr<<<dim3(24, 24, 7), dim3(32, 8), 0, stream>>>(wv, w1, wvT, w1aT, w1bT);
  k_cvt_mean<<<BN_TOT, 192, 0, stream>>>(x, xb, cb);
  // GEMM A: proj_v = xb_v @ wv_v ; xw1_v = xb_v @ w1a ; cw1 = cb @ w1b
  gemm_r<0><<<1617, 512, 73728, stream>>>(xb, cb, wvT, w1aT, w1bT, projb, xw1b, cw1);
  // GEMM B: pw1b_v = proj_v @ w1b (writes over dead xb)
  gemm_r<1><<<735, 512, 73728, stream>>>(projb, nullptr, nullptr, nullptr, w1bT,
                                         pw1b, nullptr, nullptr);
  // fused routing: 3 iterations pointwise in (b,n)
  k_iter3<<<BN_TOT, 192, 0, stream>>>(xw1b, cw1, pw1b, projb, b1, w2, outc, outr);
}